// Round 2
// baseline (318.639 us; speedup 1.0000x reference)
//
#include <hip/hip_runtime.h>
#include <hip/hip_bf16.h>
#include <stdint.h>

#define NB 2
#define NS 2048
#define NE 1024
#define NH 16
#define ND 64
#define N3 3072

typedef __attribute__((ext_vector_type(8))) short s16x8;
typedef __attribute__((ext_vector_type(4))) short s16x4;
typedef __attribute__((ext_vector_type(4))) float f32x4;

__device__ __forceinline__ float bf2f(short u){
  union { unsigned int i; float f; } v; v.i = ((unsigned int)(unsigned short)u) << 16; return v.f;
}
__device__ __forceinline__ short f2bf(float f){
  union { __hip_bfloat16 h; short s; } v; v.h = __float2bfloat16(f); return v.s;
}
__device__ __forceinline__ f32x4 mfma16(s16x8 a, s16x8 b, f32x4 c){
  return __builtin_amdgcn_mfma_f32_16x16x32_bf16(a, b, c, 0, 0, 0);
}
__device__ __forceinline__ void load_lds16(const void* g, void* l){
  __builtin_amdgcn_global_load_lds(
      (const __attribute__((address_space(1))) unsigned int*)g,
      (__attribute__((address_space(3))) unsigned int*)l, 16, 0, 0);
}

// ---------------- fp32 -> bf16 convert (vectorized) ----------------
__global__ void k_cvt(const float* __restrict__ in, short* __restrict__ out, int n4){
  int i = blockIdx.x * blockDim.x + threadIdx.x;
  if (i >= n4) return;
  float4 v = ((const float4*)in)[i];
  s16x4 o = { f2bf(v.x), f2bf(v.y), f2bf(v.z), f2bf(v.w) };
  *(s16x4*)(out + (size_t)i*4) = o;
}

// ---------------- fp32 [R][C] -> bf16 [C][R] transpose ----------------
__global__ void k_tcvt(const float* __restrict__ in, short* __restrict__ out, int R, int C){
  __shared__ float t[32][33];
  int c0 = blockIdx.x*32, r0 = blockIdx.y*32;
  int tx = threadIdx.x, ty = threadIdx.y;
  #pragma unroll
  for (int i=0;i<4;++i){
    int r = r0 + ty + i*8;
    t[ty + i*8][tx] = in[(size_t)r*C + c0 + tx];
  }
  __syncthreads();
  #pragma unroll
  for (int i=0;i<4;++i){
    int cc = c0 + ty + i*8;
    out[(size_t)cc*R + r0 + tx] = f2bf(t[tx][ty + i*8]);
  }
}

// ---------------- bf16 GEMM: C[M][N] = A[M][K] * Bt[N][K]^T + bias ----------------
template<int OUTF32>
__global__ __launch_bounds__(256) void k_gemm(const short* __restrict__ A,
    const short* __restrict__ Bt, const float* __restrict__ bias,
    short* __restrict__ outB, float* __restrict__ outF, int M, int N, int K)
{
  __shared__ short lds[128*64*2];   // A tile [128][64] then B tile [128][64]
  const int tid = threadIdx.x;
  const int lane = tid & 63, w = tid >> 6;
  const int g = lane >> 4, c = lane & 15;
  const int wm = (w >> 1) * 64, wn = (w & 1) * 64;
  const int bm = blockIdx.x * 128, bn = blockIdx.y * 128;

  f32x4 acc[4][4];
  #pragma unroll
  for (int i=0;i<4;++i)
    #pragma unroll
    for (int j=0;j<4;++j) acc[i][j] = (f32x4){0.f,0.f,0.f,0.f};

  const int nkt = K >> 6;
  for (int kt = 0; kt < nkt; ++kt){
    __syncthreads();
    #pragma unroll
    for (int i = 0; i < 8; ++i){
      const int seg   = w*8 + i;          // 0..31 ; segs 0-15 = A, 16-31 = B
      const int chunk = seg*64 + lane;    // 16-byte units
      const int local = chunk & 1023;
      const int row = local >> 3, kc = local & 7;
      const short* base = (chunk < 1024)
        ? (A  + (size_t)(bm + row) * K + kt*64)
        : (Bt + (size_t)(bn + row) * K + kt*64);
      const char* gaddr = (const char*)base + ((kc*16) ^ ((row & 7) << 4));
      load_lds16(gaddr, (char*)lds + seg*1024);
    }
    asm volatile("s_waitcnt vmcnt(0)" ::: "memory");
    __syncthreads();
    #pragma unroll
    for (int kk = 0; kk < 2; ++kk){
      s16x8 af[4], bfr[4];
      #pragma unroll
      for (int mi = 0; mi < 4; ++mi){
        int m = wm + mi*16 + c;
        int kb = (kk*64 + g*16) ^ ((m & 7) << 4);
        af[mi] = *(const s16x8*)((const char*)lds + m*128 + kb);
      }
      #pragma unroll
      for (int ni = 0; ni < 4; ++ni){
        int n = wn + ni*16 + c;
        int kb = (kk*64 + g*16) ^ ((n & 7) << 4);
        bfr[ni] = *(const s16x8*)((const char*)lds + 16384 + n*128 + kb);
      }
      #pragma unroll
      for (int mi = 0; mi < 4; ++mi)
        #pragma unroll
        for (int ni = 0; ni < 4; ++ni)
          acc[mi][ni] = mfma16(af[mi], bfr[ni], acc[mi][ni]);
    }
  }
  #pragma unroll
  for (int mi = 0; mi < 4; ++mi){
    #pragma unroll
    for (int ni = 0; ni < 4; ++ni){
      int col = bn + wn + ni*16 + c;
      float bv = bias[col];
      #pragma unroll
      for (int j = 0; j < 4; ++j){
        int rrow = bm + wm + mi*16 + g*4 + j;   // C/D: col=lane&15, row=4*(lane>>4)+j
        float v = acc[mi][ni][j] + bv;
        if (OUTF32) outF[(size_t)rrow * N + col] = v;
        else        outB[(size_t)rrow * N + col] = f2bf(v);
      }
    }
  }
}

// ---------------- RoPE on q,k parts of QKV -> Qr/Kr [B][H][S][D] ----------------
// Q is pre-scaled by softmax_scale * log2(e) so attention works in exp2 domain
// with no per-element scale multiply.
__global__ void k_rope(const short* __restrict__ qkv, short* __restrict__ Qr,
                       short* __restrict__ Kr){
  const float QSC = 0.125f * 1.44269504088896340736f;
  int idx = blockIdx.x * 256 + threadIdx.x;   // B*S*H*32 = 2,097,152
  int i = idx & 31;
  int h = (idx >> 5) & 15;
  int s = (idx >> 9) & 2047;
  int b = idx >> 20;
  float inv = __builtin_amdgcn_exp2f(-(float)i * (13.287712379549449f / 32.0f)); // 10000^(-i/32)
  float ang = (float)s * inv;
  float cs = cosf(ang), sn = sinf(ang);
  size_t base = (size_t)(b*NS + s) * N3 + h*ND + 2*i;
  float x0 = bf2f(qkv[base]),      x1 = bf2f(qkv[base+1]);
  float y0 = bf2f(qkv[base+1024]), y1 = bf2f(qkv[base+1025]);
  size_t ob = ((size_t)(b*NH + h)*NS + s) * ND + 2*i;
  Qr[ob]   = f2bf((x0*cs - x1*sn) * QSC);
  Qr[ob+1] = f2bf((x1*cs + x0*sn) * QSC);
  Kr[ob]   = f2bf(y0*cs - y1*sn);
  Kr[ob+1] = f2bf(y1*cs + y0*sn);
}

// ---------------- V part of QKV -> Vt [B][H][D][S] (transposed) ----------------
__global__ void k_vtrans(const short* __restrict__ qkv, short* __restrict__ Vt){
  __shared__ short t[64][72];
  const int bid = blockIdx.x;                 // B*H*(S/64) = 1024
  const int sb = bid & 31, h = (bid>>5) & 15, b = bid >> 9;
  const int s0 = sb * 64;
  const int tid = threadIdx.x;
  #pragma unroll
  for (int it=0; it<2; ++it){
    int u = it*256 + tid;
    int r = u >> 3, cc = (u & 7) * 8;
    s16x8 v = *(const s16x8*)(qkv + (size_t)(b*NS + s0 + r)*N3 + 2048 + h*ND + cc);
    *(s16x8*)&t[r][cc] = v;
  }
  __syncthreads();
  #pragma unroll
  for (int it=0; it<2; ++it){
    int u = it*256 + tid;
    int d = u >> 3, sc2 = (u & 7) * 8;
    s16x8 v;
    #pragma unroll
    for (int j=0;j<8;++j) v[j] = t[sc2 + j][d];
    *(s16x8*)(Vt + ((size_t)(b*NH + h)*ND + d)*NS + s0 + sc2) = v;
  }
}

// ---------------- causal flash attention ----------------
// 4 waves/block, 16 q rows/wave, KBLK=64. Swapped QK^T (S^T = mfma(K,Q)) AND
// swapped PV (O^T = mfma(V^T, P^T)) so q is the lane-local column everywhere:
// alpha/lrow rescale needs ZERO shuffles. K/V register-prefetched (issue-early).
#define PST 72   // P LDS row stride in shorts (144B: 16B-aligned, bank-uniform)
__global__ __launch_bounds__(256) void k_attn(const short* __restrict__ Qr,
    const short* __restrict__ Kr, const short* __restrict__ Vt,
    short* __restrict__ Obuf)
{
  __shared__ short plds[4][16*PST];
  const int tid = threadIdx.x;
  const int lane = tid & 63, w = tid >> 6;
  const int g = lane >> 4, c = lane & 15;
  const int bid = blockIdx.x;                 // B*H*(S/64) = 1024
  const int uu = bid & 31;
  const int qb = (uu & 1) ? (31 - (uu >> 1)) : (uu >> 1);  // balanced causal pairs
  const int h = (bid >> 5) & 15;
  const int b = bid >> 9;
  const int q0 = qb*64 + w*16;
  const int qglob = q0 + c;
  const size_t bh = (size_t)(b*NH + h);
  const short* Qbh = Qr + bh * (NS*ND);
  const short* Kbh = Kr + bh * (NS*ND);
  const short* Vbh = Vt + bh * (ND*NS);
  short* pw = &plds[w][0];

  s16x8 qf0, qf1;
  {
    const short* qp = Qbh + (size_t)(q0 + c) * ND + g*8;
    qf0 = *(const s16x8*)(qp);
    qf1 = *(const s16x8*)(qp + 32);
  }
  f32x4 acc[4];
  #pragma unroll
  for (int dt=0; dt<4; ++dt) acc[dt] = (f32x4){0.f,0.f,0.f,0.f};
  float mrow = -3.0e38f, lrow = 0.f;
  const int nkt = qb + 1;                     // uniform across the block's waves

  // prefetch tile 0 into registers
  s16x8 kf[4][2], vf[4][2];
  #pragma unroll
  for (int f=0; f<4; ++f)
    #pragma unroll
    for (int h2=0; h2<2; ++h2)
      kf[f][h2] = *(const s16x8*)(Kbh + (size_t)(f*16 + c)*ND + h2*32 + g*8);
  #pragma unroll
  for (int dt=0; dt<4; ++dt)
    #pragma unroll
    for (int kk=0; kk<2; ++kk)
      vf[dt][kk] = *(const s16x8*)(Vbh + (size_t)(dt*16 + c)*NS + kk*32 + g*8);

  for (int t = 0; t < nkt; ++t){
    const int kbase = t*64;
    const int tn = (t+1 < nkt) ? (t+1) : (nkt-1);
    // ---- QK^T: S^T[k][q], 4 row-frags x 2 d-steps ----
    f32x4 st[4];
    #pragma unroll
    for (int f=0; f<4; ++f){
      st[f] = (f32x4){0.f,0.f,0.f,0.f};
      st[f] = mfma16(kf[f][0], qf0, st[f]);
      st[f] = mfma16(kf[f][1], qf1, st[f]);
    }
    // ---- issue K(t+1) prefetch (consumed next iter) ----
    {
      const short* kpn = Kbh + (size_t)(tn*64 + c)*ND + g*8;
      #pragma unroll
      for (int f=0; f<4; ++f)
        #pragma unroll
        for (int h2=0; h2<2; ++h2)
          kf[f][h2] = *(const s16x8*)(kpn + f*16*ND + h2*32);
    }
    // ---- causal mask: only the diagonal tile needs it ----
    if (t == nkt-1){
      #pragma unroll
      for (int f=0; f<4; ++f)
        #pragma unroll
        for (int j=0; j<4; ++j){
          int kg = kbase + f*16 + g*4 + j;
          if (kg > qglob) st[f][j] = -3.0e38f;
        }
    }
    // ---- online softmax (exp2 domain; Q pre-scaled). q = c is lane-local. ----
    float tm = st[0][0];
    #pragma unroll
    for (int f=0; f<4; ++f)
      #pragma unroll
      for (int j=0; j<4; ++j) tm = fmaxf(tm, st[f][j]);
    tm = fmaxf(tm, __shfl_xor(tm, 16));
    tm = fmaxf(tm, __shfl_xor(tm, 32));
    float mn = fmaxf(mrow, tm);
    float tl = 0.f;
    float p[4][4];
    #pragma unroll
    for (int f=0; f<4; ++f)
      #pragma unroll
      for (int j=0; j<4; ++j){ p[f][j] = __builtin_amdgcn_exp2f(st[f][j] - mn); tl += p[f][j]; }
    tl += __shfl_xor(tl, 16);
    tl += __shfl_xor(tl, 32);
    float alpha = __builtin_amdgcn_exp2f(mrow - mn);
    lrow = lrow*alpha + tl;
    mrow = mn;
    #pragma unroll
    for (int dt=0; dt<4; ++dt)
      #pragma unroll
      for (int j=0; j<4; ++j) acc[dt][j] *= alpha;    // lane-local alpha: no shuffles
    // ---- P -> LDS (relayout rows k -> contiguous k per q) ----
    #pragma unroll
    for (int f=0; f<4; ++f){
      s16x4 pk = { f2bf(p[f][0]), f2bf(p[f][1]), f2bf(p[f][2]), f2bf(p[f][3]) };
      *(s16x4*)(pw + c*PST + f*16 + 4*g) = pk;        // P[q=c][k=f*16+4g+j]
    }
    asm volatile("s_waitcnt lgkmcnt(0)" ::: "memory");
    __builtin_amdgcn_sched_barrier(0);
    s16x8 pa[2];
    #pragma unroll
    for (int kk=0; kk<2; ++kk)
      pa[kk] = *(const s16x8*)(pw + c*PST + kk*32 + g*8);  // P[q=c][k=kk*32+8g+r]
    // ---- PV: O^T[d][q] += V^T[d][k] * P^T[k][q] ----
    #pragma unroll
    for (int dt=0; dt<4; ++dt)
      #pragma unroll
      for (int kk=0; kk<2; ++kk)
        acc[dt] = mfma16(vf[dt][kk], pa[kk], acc[dt]);
    // ---- issue V(t+1) prefetch ----
    {
      const short* vpn = Vbh + tn*64 + g*8;
      #pragma unroll
      for (int dt=0; dt<4; ++dt)
        #pragma unroll
        for (int kk=0; kk<2; ++kk)
          vf[dt][kk] = *(const s16x8*)(vpn + (size_t)(dt*16 + c)*NS + kk*32);
    }
  }
  const float invl = 1.f / lrow;              // lane-local (q = c)
  #pragma unroll
  for (int dt=0; dt<4; ++dt){
    s16x4 ov = { f2bf(acc[dt][0]*invl), f2bf(acc[dt][1]*invl),
                 f2bf(acc[dt][2]*invl), f2bf(acc[dt][3]*invl) };
    // O^T: row d = dt*16 + 4g + j, col q = c
    *(s16x4*)(Obuf + (size_t)(b*NS + q0 + c)*NE + h*ND + dt*16 + 4*g) = ov;
  }
}

extern "C" void kernel_launch(void* const* d_in, const int* in_sizes, int n_in,
                              void* d_out, int out_size, void* d_ws, size_t ws_size,
                              hipStream_t stream)
{
  const float* x     = (const float*)d_in[0];
  const float* w_qkv = (const float*)d_in[1];
  const float* b_qkv = (const float*)d_in[2];
  const float* w_o   = (const float*)d_in[3];
  const float* b_o   = (const float*)d_in[4];
  char* ws = (char*)d_ws;
  const size_t MB = 1u << 20;
  short* Xb    = (short*)(ws);            // 8 MB (reused as Obuf after GEMM1)
  short* Wqkvt = (short*)(ws + 8*MB);     // 6 MB
  short* Wot   = (short*)(ws + 14*MB);    // 2 MB
  short* QKV   = (short*)(ws + 16*MB);    // 24 MB
  short* Qrp   = (short*)(ws + 40*MB);    // 8 MB
  short* Krp   = (short*)(ws + 48*MB);    // 8 MB
  short* Vtp   = (short*)(ws + 56*MB);    // 8 MB  (total 64 MB)

  k_cvt<<<4096, 256, 0, stream>>>(x, Xb, (NB*NS*NE)/4);
  k_tcvt<<<dim3(N3/32, NE/32), dim3(32,8), 0, stream>>>(w_qkv, Wqkvt, NE, N3);
  k_tcvt<<<dim3(NE/32, NE/32), dim3(32,8), 0, stream>>>(w_o, Wot, NE, NE);
  k_gemm<0><<<dim3((NB*NS)/128, N3/128), 256, 0, stream>>>(Xb, Wqkvt, b_qkv, QKV, nullptr,
                                                           NB*NS, N3, NE);
  k_rope<<<(NB*NS*NH*32)/256, 256, 0, stream>>>(QKV, Qrp, Krp);
  k_vtrans<<<NB*NH*(NS/64), 256, 0, stream>>>(QKV, Vtp);
  k_attn<<<NB*NH*(NS/64), 256, 0, stream>>>(Qrp, Krp, Vtp, Xb);
  k_gemm<1><<<dim3((NB*NS)/128, NE/128), 256, 0, stream>>>(Xb, Wot, b_o, nullptr,
                                                           (float*)d_out, NB*NS, NE, NE);
}

// Round 4
// 162.662 us; speedup vs baseline: 1.9589x; 1.9589x over previous
//
#include <hip/hip_runtime.h>
#include <hip/hip_bf16.h>
#include <stdint.h>

#define NB 2
#define NS 2048
#define NE 1024
#define NH 16
#define ND 64
#define N3 3072

typedef __attribute__((ext_vector_type(8))) short s16x8;
typedef __attribute__((ext_vector_type(4))) short s16x4;
typedef __attribute__((ext_vector_type(4))) float f32x4;

__device__ __forceinline__ float bf2f(short u){
  union { unsigned int i; float f; } v; v.i = ((unsigned int)(unsigned short)u) << 16; return v.f;
}
__device__ __forceinline__ short f2bf(float f){
  union { __hip_bfloat16 h; short s; } v; v.h = __float2bfloat16(f); return v.s;
}
__device__ __forceinline__ f32x4 mfma16(s16x8 a, s16x8 b, f32x4 c){
  return __builtin_amdgcn_mfma_f32_16x16x32_bf16(a, b, c, 0, 0, 0);
}
__device__ __forceinline__ void load_lds16(const void* g, void* l){
  __builtin_amdgcn_global_load_lds(
      (const __attribute__((address_space(1))) unsigned int*)g,
      (__attribute__((address_space(3))) unsigned int*)l, 16, 0, 0);
}

// ---------------- fp32 -> bf16 convert (vectorized) ----------------
__global__ void k_cvt(const float* __restrict__ in, short* __restrict__ out, int n4){
  int i = blockIdx.x * blockDim.x + threadIdx.x;
  if (i >= n4) return;
  float4 v = ((const float4*)in)[i];
  s16x4 o = { f2bf(v.x), f2bf(v.y), f2bf(v.z), f2bf(v.w) };
  *(s16x4*)(out + (size_t)i*4) = o;
}

// ---------------- fp32 [R][C] -> bf16 [C][R] transpose ----------------
__global__ void k_tcvt(const float* __restrict__ in, short* __restrict__ out, int R, int C){
  __shared__ float t[32][33];
  int c0 = blockIdx.x*32, r0 = blockIdx.y*32;
  int tx = threadIdx.x, ty = threadIdx.y;
  #pragma unroll
  for (int i=0;i<4;++i){
    int r = r0 + ty + i*8;
    t[ty + i*8][tx] = in[(size_t)r*C + c0 + tx];
  }
  __syncthreads();
  #pragma unroll
  for (int i=0;i<4;++i){
    int cc = c0 + ty + i*8;
    out[(size_t)cc*R + r0 + tx] = f2bf(t[tx][ty + i*8]);
  }
}

// ---------------- bf16 GEMM: C[M][N] = A[M][K] * Bt[N][K]^T + bias ----------------
template<int OUTF32>
__global__ __launch_bounds__(256) void k_gemm(const short* __restrict__ A,
    const short* __restrict__ Bt, const float* __restrict__ bias,
    short* __restrict__ outB, float* __restrict__ outF, int M, int N, int K)
{
  __shared__ short lds[128*64*2];   // A tile [128][64] then B tile [128][64]
  const int tid = threadIdx.x;
  const int lane = tid & 63, w = tid >> 6;
  const int g = lane >> 4, c = lane & 15;
  const int wm = (w >> 1) * 64, wn = (w & 1) * 64;
  const int bm = blockIdx.x * 128, bn = blockIdx.y * 128;

  f32x4 acc[4][4];
  #pragma unroll
  for (int i=0;i<4;++i)
    #pragma unroll
    for (int j=0;j<4;++j) acc[i][j] = (f32x4){0.f,0.f,0.f,0.f};

  const int nkt = K >> 6;
  for (int kt = 0; kt < nkt; ++kt){
    __syncthreads();
    #pragma unroll
    for (int i = 0; i < 8; ++i){
      const int seg   = w*8 + i;          // 0..31 ; segs 0-15 = A, 16-31 = B
      const int chunk = seg*64 + lane;    // 16-byte units
      const int local = chunk & 1023;
      const int row = local >> 3, kc = local & 7;
      const short* base = (chunk < 1024)
        ? (A  + (size_t)(bm + row) * K + kt*64)
        : (Bt + (size_t)(bn + row) * K + kt*64);
      const char* gaddr = (const char*)base + ((kc*16) ^ ((row & 7) << 4));
      load_lds16(gaddr, (char*)lds + seg*1024);
    }
    asm volatile("s_waitcnt vmcnt(0)" ::: "memory");
    __syncthreads();
    #pragma unroll
    for (int kk = 0; kk < 2; ++kk){
      s16x8 af[4], bfr[4];
      #pragma unroll
      for (int mi = 0; mi < 4; ++mi){
        int m = wm + mi*16 + c;
        int kb = (kk*64 + g*16) ^ ((m & 7) << 4);
        af[mi] = *(const s16x8*)((const char*)lds + m*128 + kb);
      }
      #pragma unroll
      for (int ni = 0; ni < 4; ++ni){
        int n = wn + ni*16 + c;
        int kb = (kk*64 + g*16) ^ ((n & 7) << 4);
        bfr[ni] = *(const s16x8*)((const char*)lds + 16384 + n*128 + kb);
      }
      #pragma unroll
      for (int mi = 0; mi < 4; ++mi)
        #pragma unroll
        for (int ni = 0; ni < 4; ++ni)
          acc[mi][ni] = mfma16(af[mi], bfr[ni], acc[mi][ni]);
    }
  }
  #pragma unroll
  for (int mi = 0; mi < 4; ++mi){
    #pragma unroll
    for (int ni = 0; ni < 4; ++ni){
      int col = bn + wn + ni*16 + c;
      float bv = bias[col];
      #pragma unroll
      for (int j = 0; j < 4; ++j){
        int rrow = bm + wm + mi*16 + g*4 + j;   // C/D: col=lane&15, row=4*(lane>>4)+j
        float v = acc[mi][ni][j] + bv;
        if (OUTF32) outF[(size_t)rrow * N + col] = v;
        else        outB[(size_t)rrow * N + col] = f2bf(v);
      }
    }
  }
}

// ---------------- RoPE on q,k parts of QKV -> Qr/Kr [B][H][S][D] ----------------
// Q pre-scaled by softmax_scale * log2(e): attention runs in exp2 domain.
__global__ void k_rope(const short* __restrict__ qkv, short* __restrict__ Qr,
                       short* __restrict__ Kr){
  const float QSC = 0.125f * 1.44269504088896340736f;
  int idx = blockIdx.x * 256 + threadIdx.x;   // B*S*H*32 = 2,097,152
  int i = idx & 31;
  int h = (idx >> 5) & 15;
  int s = (idx >> 9) & 2047;
  int b = idx >> 20;
  float inv = __builtin_amdgcn_exp2f(-(float)i * (13.287712379549449f / 32.0f)); // 10000^(-i/32)
  float ang = (float)s * inv;
  float cs = cosf(ang), sn = sinf(ang);
  size_t base = (size_t)(b*NS + s) * N3 + h*ND + 2*i;
  float x0 = bf2f(qkv[base]),      x1 = bf2f(qkv[base+1]);
  float y0 = bf2f(qkv[base+1024]), y1 = bf2f(qkv[base+1025]);
  size_t ob = ((size_t)(b*NH + h)*NS + s) * ND + 2*i;
  Qr[ob]   = f2bf((x0*cs - x1*sn) * QSC);
  Qr[ob+1] = f2bf((x1*cs + x0*sn) * QSC);
  Kr[ob]   = f2bf(y0*cs - y1*sn);
  Kr[ob+1] = f2bf(y1*cs + y0*sn);
}

// ---------------- V part of QKV -> Vt [B][H][D][S] (transposed) ----------------
__global__ void k_vtrans(const short* __restrict__ qkv, short* __restrict__ Vt){
  __shared__ short t[64][72];
  const int bid = blockIdx.x;                 // B*H*(S/64) = 1024
  const int sb = bid & 31, h = (bid>>5) & 15, b = bid >> 9;
  const int s0 = sb * 64;
  const int tid = threadIdx.x;
  #pragma unroll
  for (int it=0; it<2; ++it){
    int u = it*256 + tid;
    int r = u >> 3, cc = (u & 7) * 8;
    s16x8 v = *(const s16x8*)(qkv + (size_t)(b*NS + s0 + r)*N3 + 2048 + h*ND + cc);
    *(s16x8*)&t[r][cc] = v;
  }
  __syncthreads();
  #pragma unroll
  for (int it=0; it<2; ++it){
    int u = it*256 + tid;
    int d = u >> 3, sc2 = (u & 7) * 8;
    s16x8 v;
    #pragma unroll
    for (int j=0;j<8;++j) v[j] = t[sc2 + j][d];
    *(s16x8*)(Vt + ((size_t)(b*NH + h)*ND + d)*NS + s0 + sc2) = v;
  }
}

// ---------------- causal flash attention ----------------
// 4 waves/block, QBLK=64 (16 q/wave), KBLK=64. K/V staged ONCE per block into
// double-buffered LDS via global_load_lds (XOR-swizzled source), counted-vmcnt
// pipeline with raw s_barrier (m201 pattern). Swapped QK^T and PV keep q
// lane-local (zero-shuffle rescale).
#define PST 72   // P LDS row stride in shorts (>= KBLK=64; 144B rows keep 16B-aligned s16x8 reads)
__global__ __launch_bounds__(256) void k_attn(const short* __restrict__ Qr,
    const short* __restrict__ Kr, const short* __restrict__ Vt,
    short* __restrict__ Obuf)
{
  __shared__ short Kb[2][64*64];              // 16 KB
  __shared__ short Vb[2][64*64];              // 16 KB
  __shared__ short plds[4][16*PST];           // 9 KB
  const int tid = threadIdx.x;
  const int lane = tid & 63, w = tid >> 6;
  const int g = lane >> 4, c = lane & 15;
  const int bid = blockIdx.x;                 // B*H*(S/64) = 1024
  const int uu = bid & 31;
  const int h = (bid >> 5) & 15;
  const int b = bid >> 9;
  const int qb = (uu + h) & 31;   // XCD = bid%8 = uu%8 -> every XCD gets balanced qb mix
  const int q0 = qb*64 + w*16;
  const int qglob = q0 + c;
  const size_t bh = (size_t)(b*NH + h);
  const short* Qbh = Qr + bh * (NS*ND);
  const short* Kbh = Kr + bh * (NS*ND);
  const short* Vbh = Vt + bh * (ND*NS);
  short* pw = &plds[w][0];
  const int nkt = qb + 1;                     // uniform across the block's waves

  s16x8 qf0, qf1;
  {
    const short* qp = Qbh + (size_t)(q0 + c) * ND + g*8;
    qf0 = *(const s16x8*)(qp);
    qf1 = *(const s16x8*)(qp + 32);
  }
  f32x4 acc[4];
  #pragma unroll
  for (int dt=0; dt<4; ++dt) acc[dt] = (f32x4){0.f,0.f,0.f,0.f};
  float mrow = -3.0e38f, lrow = 0.f;

  // stage tile tt into buffer bsel: K tile [64 rows][64 k] + V tile [64 d][64 k],
  // both row-major 128B rows, source pre-swizzled by ((row&7)<<4).
  auto STAGE = [&](int tt, int bsel){
    const int kb64 = tt*64;
    #pragma unroll
    for (int i=0;i<2;++i){
      int u = w*128 + i*64 + lane;            // 16B-chunk index, 0..511
      int r = u >> 3, kc = u & 7;
      int sw = (kc*16) ^ ((r & 7) << 4);
      const char* srcK = (const char*)(Kbh + (size_t)(kb64 + r)*ND) + sw;
      load_lds16(srcK, (char*)&Kb[bsel][0] + w*2048 + i*1024);
      const char* srcV = (const char*)(Vbh + (size_t)r*NS + kb64) + sw;
      load_lds16(srcV, (char*)&Vb[bsel][0] + w*2048 + i*1024);
    }
  };

  STAGE(0, 0);
  for (int t = 0; t < nkt; ++t){
    const int cur = t & 1;
    if (t + 1 < nkt){
      STAGE(t + 1, cur ^ 1);
      asm volatile("s_waitcnt vmcnt(4)" ::: "memory");   // retire stage(t), keep t+1 in flight
    } else {
      asm volatile("s_waitcnt vmcnt(0)" ::: "memory");
    }
    __builtin_amdgcn_s_barrier();             // raw: no implicit vmcnt(0) drain
    __builtin_amdgcn_sched_barrier(0);
    const short* Kc = &Kb[cur][0];
    const short* Vc = &Vb[cur][0];
    // ---- QK^T: S^T[k][q] ----
    f32x4 st[4];
    #pragma unroll
    for (int f=0; f<4; ++f){
      const char* kp = (const char*)Kc + (f*16 + c)*128;
      s16x8 k0 = *(const s16x8*)(kp + ((g*16)      ^ ((c & 7) << 4)));
      s16x8 k1 = *(const s16x8*)(kp + ((64 + g*16) ^ ((c & 7) << 4)));
      st[f] = (f32x4){0.f,0.f,0.f,0.f};
      st[f] = mfma16(k0, qf0, st[f]);
      st[f] = mfma16(k1, qf1, st[f]);
    }
    // ---- causal mask: only the diagonal tile ----
    if (t == nkt-1){
      #pragma unroll
      for (int f=0; f<4; ++f)
        #pragma unroll
        for (int j=0; j<4; ++j){
          int kg = t*64 + f*16 + g*4 + j;
          if (kg > qglob) st[f][j] = -3.0e38f;
        }
    }
    // ---- online softmax (exp2 domain; q = c lane-local) ----
    float tm = st[0][0];
    #pragma unroll
    for (int f=0; f<4; ++f)
      #pragma unroll
      for (int j=0; j<4; ++j) tm = fmaxf(tm, st[f][j]);
    tm = fmaxf(tm, __shfl_xor(tm, 16));
    tm = fmaxf(tm, __shfl_xor(tm, 32));
    float mn = fmaxf(mrow, tm);
    float tl = 0.f;
    float p[4][4];
    #pragma unroll
    for (int f=0; f<4; ++f)
      #pragma unroll
      for (int j=0; j<4; ++j){ p[f][j] = __builtin_amdgcn_exp2f(st[f][j] - mn); tl += p[f][j]; }
    tl += __shfl_xor(tl, 16);
    tl += __shfl_xor(tl, 32);
    float alpha = __builtin_amdgcn_exp2f(mrow - mn);
    lrow = lrow*alpha + tl;
    mrow = mn;
    #pragma unroll
    for (int dt=0; dt<4; ++dt)
      #pragma unroll
      for (int j=0; j<4; ++j) acc[dt][j] *= alpha;   // lane-local alpha
    // ---- P -> LDS relayout (k-frags -> contiguous k per q) ----
    #pragma unroll
    for (int f=0; f<4; ++f){
      s16x4 pk = { f2bf(p[f][0]), f2bf(p[f][1]), f2bf(p[f][2]), f2bf(p[f][3]) };
      *(s16x4*)(pw + c*PST + f*16 + 4*g) = pk;       // P[q=c][k=f*16+4g+j]
    }
    asm volatile("s_waitcnt lgkmcnt(0)" ::: "memory");
    __builtin_amdgcn_sched_barrier(0);
    s16x8 pa[2];
    #pragma unroll
    for (int kk=0; kk<2; ++kk)
      pa[kk] = *(const s16x8*)(pw + c*PST + kk*32 + g*8);
    // ---- PV: O^T[d][q] += V^T[d][k] * P^T[k][q] ----
    #pragma unroll
    for (int dt=0; dt<4; ++dt){
      const char* vp = (const char*)Vc + (dt*16 + c)*128;
      #pragma unroll
      for (int kk=0; kk<2; ++kk){
        s16x8 vfr = *(const s16x8*)(vp + ((kk*64 + g*16) ^ ((c & 7) << 4)));
        acc[dt] = mfma16(vfr, pa[kk], acc[dt]);
      }
    }
    __builtin_amdgcn_sched_barrier(0);
    __builtin_amdgcn_s_barrier();             // all waves done reading buf before overwrite
  }
  const float invl = 1.f / lrow;              // lane-local (q = c)
  #pragma unroll
  for (int dt=0; dt<4; ++dt){
    s16x4 ov = { f2bf(acc[dt][0]*invl), f2bf(acc[dt][1]*invl),
                 f2bf(acc[dt][2]*invl), f2bf(acc[dt][3]*invl) };
    *(s16x4*)(Obuf + (size_t)(b*NS + q0 + c)*NE + h*ND + dt*16 + 4*g) = ov;
  }
}

extern "C" void kernel_launch(void* const* d_in, const int* in_sizes, int n_in,
                              void* d_out, int out_size, void* d_ws, size_t ws_size,
                              hipStream_t stream)
{
  const float* x     = (const float*)d_in[0];
  const float* w_qkv = (const float*)d_in[1];
  const float* b_qkv = (const float*)d_in[2];
  const float* w_o   = (const float*)d_in[3];
  const float* b_o   = (const float*)d_in[4];
  char* ws = (char*)d_ws;
  const size_t MB = 1u << 20;
  short* Xb    = (short*)(ws);            // 8 MB (reused as Obuf after GEMM1)
  short* Wqkvt = (short*)(ws + 8*MB);     // 6 MB
  short* Wot   = (short*)(ws + 14*MB);    // 2 MB
  short* QKV   = (short*)(ws + 16*MB);    // 24 MB
  short* Qrp   = (short*)(ws + 40*MB);    // 8 MB
  short* Krp   = (short*)(ws + 48*MB);    // 8 MB
  short* Vtp   = (short*)(ws + 56*MB);    // 8 MB  (total 64 MB)

  k_cvt<<<4096, 256, 0, stream>>>(x, Xb, (NB*NS*NE)/4);
  k_tcvt<<<dim3(N3/32, NE/32), dim3(32,8), 0, stream>>>(w_qkv, Wqkvt, NE, N3);
  k_tcvt<<<dim3(NE/32, NE/32), dim3(32,8), 0, stream>>>(w_o, Wot, NE, NE);
  k_gemm<0><<<dim3((NB*NS)/128, N3/128), 256, 0, stream>>>(Xb, Wqkvt, b_qkv, QKV, nullptr,
                                                           NB*NS, N3, NE);
  k_rope<<<(NB*NS*NH*32)/256, 256, 0, stream>>>(QKV, Qrp, Krp);
  k_vtrans<<<NB*NH*(NS/64), 256, 0, stream>>>(QKV, Vtp);
  k_attn<<<NB*NH*(NS/64), 256, 0, stream>>>(Qrp, Krp, Vtp, Xb);
  k_gemm<1><<<dim3((NB*NS)/128, NE/128), 256, 0, stream>>>(Xb, Wot, b_o, nullptr,
                                                           (float*)d_out, NB*NS, NE, NE);
}

// Round 5
// 144.354 us; speedup vs baseline: 2.2073x; 1.1268x over previous
//
#include <hip/hip_runtime.h>
#include <hip/hip_bf16.h>
#include <stdint.h>

#define NB 2
#define NS 2048
#define NE 1024
#define NH 16
#define ND 64
#define N3 3072

typedef __attribute__((ext_vector_type(8))) short s16x8;
typedef __attribute__((ext_vector_type(4))) short s16x4;
typedef __attribute__((ext_vector_type(4))) float f32x4;

__device__ __forceinline__ float bf2f(short u){
  union { unsigned int i; float f; } v; v.i = ((unsigned int)(unsigned short)u) << 16; return v.f;
}
__device__ __forceinline__ short f2bf(float f){
  union { __hip_bfloat16 h; short s; } v; v.h = __float2bfloat16(f); return v.s;
}
__device__ __forceinline__ f32x4 mfma16(s16x8 a, s16x8 b, f32x4 c){
  return __builtin_amdgcn_mfma_f32_16x16x32_bf16(a, b, c, 0, 0, 0);
}
__device__ __forceinline__ void load_lds16(const void* g, void* l){
  __builtin_amdgcn_global_load_lds(
      (const __attribute__((address_space(1))) unsigned int*)g,
      (__attribute__((address_space(3))) unsigned int*)l, 16, 0, 0);
}

// ---------------- fp32 -> bf16 convert (vectorized) ----------------
__global__ void k_cvt(const float* __restrict__ in, short* __restrict__ out, int n4){
  int i = blockIdx.x * blockDim.x + threadIdx.x;
  if (i >= n4) return;
  float4 v = ((const float4*)in)[i];
  s16x4 o = { f2bf(v.x), f2bf(v.y), f2bf(v.z), f2bf(v.w) };
  *(s16x4*)(out + (size_t)i*4) = o;
}

// ---------------- fp32 [R][C] -> bf16 [C][R] transpose ----------------
__global__ void k_tcvt(const float* __restrict__ in, short* __restrict__ out, int R, int C){
  __shared__ float t[32][33];
  int c0 = blockIdx.x*32, r0 = blockIdx.y*32;
  int tx = threadIdx.x, ty = threadIdx.y;
  #pragma unroll
  for (int i=0;i<4;++i){
    int r = r0 + ty + i*8;
    t[ty + i*8][tx] = in[(size_t)r*C + c0 + tx];
  }
  __syncthreads();
  #pragma unroll
  for (int i=0;i<4;++i){
    int cc = c0 + ty + i*8;
    out[(size_t)cc*R + r0 + tx] = f2bf(t[tx][ty + i*8]);
  }
}

// ---------------- bf16 GEMM: C[M][N] = A[M][K] * Bt[N][K]^T + bias ----------------
template<int OUTF32>
__global__ __launch_bounds__(256) void k_gemm(const short* __restrict__ A,
    const short* __restrict__ Bt, const float* __restrict__ bias,
    short* __restrict__ outB, float* __restrict__ outF, int M, int N, int K)
{
  __shared__ short lds[128*64*2];   // A tile [128][64] then B tile [128][64]
  const int tid = threadIdx.x;
  const int lane = tid & 63, w = tid >> 6;
  const int g = lane >> 4, c = lane & 15;
  const int wm = (w >> 1) * 64, wn = (w & 1) * 64;
  const int bm = blockIdx.x * 128, bn = blockIdx.y * 128;

  f32x4 acc[4][4];
  #pragma unroll
  for (int i=0;i<4;++i)
    #pragma unroll
    for (int j=0;j<4;++j) acc[i][j] = (f32x4){0.f,0.f,0.f,0.f};

  const int nkt = K >> 6;
  for (int kt = 0; kt < nkt; ++kt){
    __syncthreads();
    #pragma unroll
    for (int i = 0; i < 8; ++i){
      const int seg   = w*8 + i;          // 0..31 ; segs 0-15 = A, 16-31 = B
      const int chunk = seg*64 + lane;    // 16-byte units
      const int local = chunk & 1023;
      const int row = local >> 3, kc = local & 7;
      const short* base = (chunk < 1024)
        ? (A  + (size_t)(bm + row) * K + kt*64)
        : (Bt + (size_t)(bn + row) * K + kt*64);
      const char* gaddr = (const char*)base + ((kc*16) ^ ((row & 7) << 4));
      load_lds16(gaddr, (char*)lds + seg*1024);
    }
    asm volatile("s_waitcnt vmcnt(0)" ::: "memory");
    __syncthreads();
    #pragma unroll
    for (int kk = 0; kk < 2; ++kk){
      s16x8 af[4], bfr[4];
      #pragma unroll
      for (int mi = 0; mi < 4; ++mi){
        int m = wm + mi*16 + c;
        int kb = (kk*64 + g*16) ^ ((m & 7) << 4);
        af[mi] = *(const s16x8*)((const char*)lds + m*128 + kb);
      }
      #pragma unroll
      for (int ni = 0; ni < 4; ++ni){
        int n = wn + ni*16 + c;
        int kb = (kk*64 + g*16) ^ ((n & 7) << 4);
        bfr[ni] = *(const s16x8*)((const char*)lds + 16384 + n*128 + kb);
      }
      #pragma unroll
      for (int mi = 0; mi < 4; ++mi)
        #pragma unroll
        for (int ni = 0; ni < 4; ++ni)
          acc[mi][ni] = mfma16(af[mi], bfr[ni], acc[mi][ni]);
    }
  }
  #pragma unroll
  for (int mi = 0; mi < 4; ++mi){
    #pragma unroll
    for (int ni = 0; ni < 4; ++ni){
      int col = bn + wn + ni*16 + c;
      float bv = bias[col];
      #pragma unroll
      for (int j = 0; j < 4; ++j){
        int rrow = bm + wm + mi*16 + g*4 + j;   // C/D: col=lane&15, row=4*(lane>>4)+j
        float v = acc[mi][ni][j] + bv;
        if (OUTF32) outF[(size_t)rrow * N + col] = v;
        else        outB[(size_t)rrow * N + col] = f2bf(v);
      }
    }
  }
}

// ---------------- RoPE on q,k parts of QKV -> Qr/Kr [B][H][S][D] ----------------
// Q pre-scaled by softmax_scale * log2(e): attention runs in exp2 domain.
__global__ void k_rope(const short* __restrict__ qkv, short* __restrict__ Qr,
                       short* __restrict__ Kr){
  const float QSC = 0.125f * 1.44269504088896340736f;
  int idx = blockIdx.x * 256 + threadIdx.x;   // B*S*H*32 = 2,097,152
  int i = idx & 31;
  int h = (idx >> 5) & 15;
  int s = (idx >> 9) & 2047;
  int b = idx >> 20;
  float inv = __builtin_amdgcn_exp2f(-(float)i * (13.287712379549449f / 32.0f)); // 10000^(-i/32)
  float ang = (float)s * inv;
  float cs = cosf(ang), sn = sinf(ang);
  size_t base = (size_t)(b*NS + s) * N3 + h*ND + 2*i;
  float x0 = bf2f(qkv[base]),      x1 = bf2f(qkv[base+1]);
  float y0 = bf2f(qkv[base+1024]), y1 = bf2f(qkv[base+1025]);
  size_t ob = ((size_t)(b*NH + h)*NS + s) * ND + 2*i;
  Qr[ob]   = f2bf((x0*cs - x1*sn) * QSC);
  Qr[ob+1] = f2bf((x1*cs + x0*sn) * QSC);
  Kr[ob]   = f2bf(y0*cs - y1*sn);
  Kr[ob+1] = f2bf(y1*cs + y0*sn);
}

// ---------------- V part of QKV -> Vt [B][H][D][S] (transposed) ----------------
__global__ void k_vtrans(const short* __restrict__ qkv, short* __restrict__ Vt){
  __shared__ short t[64][72];
  const int bid = blockIdx.x;                 // B*H*(S/64) = 1024
  const int sb = bid & 31, h = (bid>>5) & 15, b = bid >> 9;
  const int s0 = sb * 64;
  const int tid = threadIdx.x;
  #pragma unroll
  for (int it=0; it<2; ++it){
    int u = it*256 + tid;
    int r = u >> 3, cc = (u & 7) * 8;
    s16x8 v = *(const s16x8*)(qkv + (size_t)(b*NS + s0 + r)*N3 + 2048 + h*ND + cc);
    *(s16x8*)&t[r][cc] = v;
  }
  __syncthreads();
  #pragma unroll
  for (int it=0; it<2; ++it){
    int u = it*256 + tid;
    int d = u >> 3, sc2 = (u & 7) * 8;
    s16x8 v;
    #pragma unroll
    for (int j=0;j<8;++j) v[j] = t[sc2 + j][d];
    *(s16x8*)(Vt + ((size_t)(b*NH + h)*ND + d)*NS + s0 + sc2) = v;
  }
}

// ---------------- causal flash attention ----------------
// 4 waves/block. Each block handles TWO q-tiles (qb, 31-qb) sequentially ->
// uniform cost 33 K-tiles/block, zero tail. Triple-buffered K/V LDS staging
// (global_load_lds, XOR-swizzled source), prefetch depth 2 with counted
// vmcnt(8/4/0), raw s_barrier pair per iter. Swapped QK^T and PV keep q
// lane-local (zero-shuffle softmax rescale).
#define PST 72   // P LDS row stride in shorts (>= KBLK=64; 144B rows keep 16B-aligned s16x8 reads)
__global__ __launch_bounds__(256) void k_attn(const short* __restrict__ Qr,
    const short* __restrict__ Kr, const short* __restrict__ Vt,
    short* __restrict__ Obuf)
{
  __shared__ short Kb[3][64*64];              // 24 KB
  __shared__ short Vb[3][64*64];              // 24 KB
  __shared__ short plds[4][16*PST];           // 9 KB
  const int tid = threadIdx.x;
  const int lane = tid & 63, w = tid >> 6;
  const int g = lane >> 4, c = lane & 15;
  const int bid = blockIdx.x;                 // B*H*16 = 512
  const int pid = bid & 15;
  const int h = (bid >> 4) & 15;
  const int b = bid >> 8;
  const size_t bh = (size_t)(b*NH + h);
  const short* Qbh = Qr + bh * (NS*ND);
  const short* Kbh = Kr + bh * (NS*ND);
  const short* Vbh = Vt + bh * (ND*NS);
  short* pw = &plds[w][0];

  // stage tile tt into buffer bsel: K tile [64 rows][64 k] + V tile [64 d][64 k],
  // both row-major 128B rows, source pre-swizzled by ((row&7)<<4). 4 loads/wave.
  auto STAGE = [&](int tt, int bsel){
    const int kb64 = tt*64;
    #pragma unroll
    for (int i=0;i<2;++i){
      int u = w*128 + i*64 + lane;            // 16B-chunk index, 0..511
      int r = u >> 3, kc = u & 7;
      int sw = (kc*16) ^ ((r & 7) << 4);
      const char* srcK = (const char*)(Kbh + (size_t)(kb64 + r)*ND) + sw;
      load_lds16(srcK, (char*)&Kb[bsel][0] + w*2048 + i*1024);
      const char* srcV = (const char*)(Vbh + (size_t)r*NS + kb64) + sw;
      load_lds16(srcV, (char*)&Vb[bsel][0] + w*2048 + i*1024);
    }
  };

  for (int ph = 0; ph < 2; ++ph){
    const int qb = ph ? (31 - pid) : pid;     // pair sums to 33 tiles -> uniform cost
    const int q0 = qb*64 + w*16;
    const int qglob = q0 + c;
    const int nkt = qb + 1;                   // uniform across the block's waves

    s16x8 qf0, qf1;
    {
      const short* qp = Qbh + (size_t)(q0 + c) * ND + g*8;
      qf0 = *(const s16x8*)(qp);
      qf1 = *(const s16x8*)(qp + 32);
    }
    f32x4 acc[4];
    #pragma unroll
    for (int dt=0; dt<4; ++dt) acc[dt] = (f32x4){0.f,0.f,0.f,0.f};
    float mrow = -3.0e38f, lrow = 0.f;

    STAGE(0, 0);
    if (nkt > 1) STAGE(1, 1);
    for (int t = 0; t < nkt; ++t){
      const int cur = t % 3;
      if (t + 2 < nkt){
        STAGE(t + 2, (t + 2) % 3);
        asm volatile("s_waitcnt vmcnt(8)" ::: "memory");  // stage(t) retired; t+1,t+2 in flight
      } else if (t + 1 < nkt){
        asm volatile("s_waitcnt vmcnt(4)" ::: "memory");  // stage(t) retired; t+1 in flight
      } else {
        asm volatile("s_waitcnt vmcnt(0)" ::: "memory");  // full drain on last tile
      }
      __builtin_amdgcn_s_barrier();           // raw: no implicit vmcnt(0) drain
      __builtin_amdgcn_sched_barrier(0);
      const short* Kc = &Kb[cur][0];
      const short* Vc = &Vb[cur][0];
      // ---- QK^T: S^T[k][q] ----
      f32x4 st[4];
      __builtin_amdgcn_s_setprio(1);
      #pragma unroll
      for (int f=0; f<4; ++f){
        const char* kp = (const char*)Kc + (f*16 + c)*128;
        s16x8 k0 = *(const s16x8*)(kp + ((g*16)      ^ ((c & 7) << 4)));
        s16x8 k1 = *(const s16x8*)(kp + ((64 + g*16) ^ ((c & 7) << 4)));
        st[f] = (f32x4){0.f,0.f,0.f,0.f};
        st[f] = mfma16(k0, qf0, st[f]);
        st[f] = mfma16(k1, qf1, st[f]);
      }
      __builtin_amdgcn_s_setprio(0);
      // ---- causal mask: only the diagonal tile ----
      if (t == nkt-1){
        #pragma unroll
        for (int f=0; f<4; ++f)
          #pragma unroll
          for (int j=0; j<4; ++j){
            int kg = t*64 + f*16 + g*4 + j;
            if (kg > qglob) st[f][j] = -3.0e38f;
          }
      }
      // ---- online softmax (exp2 domain; q = c lane-local); tree reductions ----
      float mf[4];
      #pragma unroll
      for (int f=0; f<4; ++f)
        mf[f] = fmaxf(fmaxf(st[f][0], st[f][1]), fmaxf(st[f][2], st[f][3]));
      float tm = fmaxf(fmaxf(mf[0], mf[1]), fmaxf(mf[2], mf[3]));
      tm = fmaxf(tm, __shfl_xor(tm, 16));
      tm = fmaxf(tm, __shfl_xor(tm, 32));
      float mn = fmaxf(mrow, tm);
      float p[4][4];
      #pragma unroll
      for (int f=0; f<4; ++f)
        #pragma unroll
        for (int j=0; j<4; ++j) p[f][j] = __builtin_amdgcn_exp2f(st[f][j] - mn);
      float sf[4];
      #pragma unroll
      for (int f=0; f<4; ++f)
        sf[f] = (p[f][0] + p[f][1]) + (p[f][2] + p[f][3]);
      float tl = (sf[0] + sf[1]) + (sf[2] + sf[3]);
      tl += __shfl_xor(tl, 16);
      tl += __shfl_xor(tl, 32);
      float alpha = __builtin_amdgcn_exp2f(mrow - mn);
      lrow = lrow*alpha + tl;
      mrow = mn;
      #pragma unroll
      for (int dt=0; dt<4; ++dt)
        #pragma unroll
        for (int j=0; j<4; ++j) acc[dt][j] *= alpha;   // lane-local alpha
      // ---- P -> LDS relayout (k-frags -> contiguous k per q) ----
      #pragma unroll
      for (int f=0; f<4; ++f){
        s16x4 pk = { f2bf(p[f][0]), f2bf(p[f][1]), f2bf(p[f][2]), f2bf(p[f][3]) };
        *(s16x4*)(pw + c*PST + f*16 + 4*g) = pk;       // P[q=c][k=f*16+4g+j]
      }
      asm volatile("s_waitcnt lgkmcnt(0)" ::: "memory");
      __builtin_amdgcn_sched_barrier(0);
      s16x8 pa[2];
      #pragma unroll
      for (int kk=0; kk<2; ++kk)
        pa[kk] = *(const s16x8*)(pw + c*PST + kk*32 + g*8);
      // ---- PV: O^T[d][q] += V^T[d][k] * P^T[k][q] ----
      __builtin_amdgcn_s_setprio(1);
      #pragma unroll
      for (int dt=0; dt<4; ++dt){
        const char* vp = (const char*)Vc + (dt*16 + c)*128;
        #pragma unroll
        for (int kk=0; kk<2; ++kk){
          s16x8 vfr = *(const s16x8*)(vp + ((kk*64 + g*16) ^ ((c & 7) << 4)));
          acc[dt] = mfma16(vfr, pa[kk], acc[dt]);
        }
      }
      __builtin_amdgcn_s_setprio(0);
      __builtin_amdgcn_sched_barrier(0);
      __builtin_amdgcn_s_barrier();           // all waves done reading buf before overwrite
    }
    const float invl = 1.f / lrow;            // lane-local (q = c)
    #pragma unroll
    for (int dt=0; dt<4; ++dt){
      s16x4 ov = { f2bf(acc[dt][0]*invl), f2bf(acc[dt][1]*invl),
                   f2bf(acc[dt][2]*invl), f2bf(acc[dt][3]*invl) };
      *(s16x4*)(Obuf + (size_t)(b*NS + q0 + c)*NE + h*ND + dt*16 + 4*g) = ov;
    }
  }
}

extern "C" void kernel_launch(void* const* d_in, const int* in_sizes, int n_in,
                              void* d_out, int out_size, void* d_ws, size_t ws_size,
                              hipStream_t stream)
{
  const float* x     = (const float*)d_in[0];
  const float* w_qkv = (const float*)d_in[1];
  const float* b_qkv = (const float*)d_in[2];
  const float* w_o   = (const float*)d_in[3];
  const float* b_o   = (const float*)d_in[4];
  char* ws = (char*)d_ws;
  const size_t MB = 1u << 20;
  short* Xb    = (short*)(ws);            // 8 MB (reused as Obuf after GEMM1)
  short* Wqkvt = (short*)(ws + 8*MB);     // 6 MB
  short* Wot   = (short*)(ws + 14*MB);    // 2 MB
  short* QKV   = (short*)(ws + 16*MB);    // 24 MB
  short* Qrp   = (short*)(ws + 40*MB);    // 8 MB
  short* Krp   = (short*)(ws + 48*MB);    // 8 MB
  short* Vtp   = (short*)(ws + 56*MB);    // 8 MB  (total 64 MB)

  k_cvt<<<4096, 256, 0, stream>>>(x, Xb, (NB*NS*NE)/4);
  k_tcvt<<<dim3(N3/32, NE/32), dim3(32,8), 0, stream>>>(w_qkv, Wqkvt, NE, N3);
  k_tcvt<<<dim3(NE/32, NE/32), dim3(32,8), 0, stream>>>(w_o, Wot, NE, NE);
  k_gemm<0><<<dim3((NB*NS)/128, N3/128), 256, 0, stream>>>(Xb, Wqkvt, b_qkv, QKV, nullptr,
                                                           NB*NS, N3, NE);
  k_rope<<<(NB*NS*NH*32)/256, 256, 0, stream>>>(QKV, Qrp, Krp);
  k_vtrans<<<NB*NH*(NS/64), 256, 0, stream>>>(QKV, Vtp);
  k_attn<<<NB*NH*16, 256, 0, stream>>>(Qrp, Krp, Vtp, Xb);
  k_gemm<1><<<dim3((NB*NS)/128, NE/128), 256, 0, stream>>>(Xb, Wot, b_o, nullptr,
                                                           (float*)d_out, NB*NS, NE, NE);
}

// Round 6
// 137.994 us; speedup vs baseline: 2.3091x; 1.0461x over previous
//
#include <hip/hip_runtime.h>
#include <hip/hip_bf16.h>
#include <stdint.h>

#define NB 2
#define NS 2048
#define NE 1024
#define NH 16
#define ND 64
#define N3 3072

typedef __attribute__((ext_vector_type(8))) short s16x8;
typedef __attribute__((ext_vector_type(4))) short s16x4;
typedef __attribute__((ext_vector_type(4))) float f32x4;
typedef __attribute__((ext_vector_type(2))) unsigned int u32x2;

__device__ __forceinline__ float bf2f(short u){
  union { unsigned int i; float f; } v; v.i = ((unsigned int)(unsigned short)u) << 16; return v.f;
}
__device__ __forceinline__ short f2bf(float f){
  union { __hip_bfloat16 h; short s; } v; v.h = __float2bfloat16(f); return v.s;
}
__device__ __forceinline__ f32x4 mfma16(s16x8 a, s16x8 b, f32x4 c){
  return __builtin_amdgcn_mfma_f32_16x16x32_bf16(a, b, c, 0, 0, 0);
}
__device__ __forceinline__ void load_lds16(const void* g, void* l){
  __builtin_amdgcn_global_load_lds(
      (const __attribute__((address_space(1))) unsigned int*)g,
      (__attribute__((address_space(3))) unsigned int*)l, 16, 0, 0);
}
// 64-lane reductions via permlane swaps (VALU, no LDS pipe)
__device__ __forceinline__ float redmax64(float v){
  u32x2 a = __builtin_amdgcn_permlane16_swap(__float_as_uint(v), __float_as_uint(v), false, false);
  v = fmaxf(__uint_as_float(a[0]), __uint_as_float(a[1]));
  u32x2 b = __builtin_amdgcn_permlane32_swap(__float_as_uint(v), __float_as_uint(v), false, false);
  return fmaxf(__uint_as_float(b[0]), __uint_as_float(b[1]));
}
__device__ __forceinline__ float redsum64(float v){
  u32x2 a = __builtin_amdgcn_permlane16_swap(__float_as_uint(v), __float_as_uint(v), false, false);
  v = __uint_as_float(a[0]) + __uint_as_float(a[1]);
  u32x2 b = __builtin_amdgcn_permlane32_swap(__float_as_uint(v), __float_as_uint(v), false, false);
  return __uint_as_float(b[0]) + __uint_as_float(b[1]);
}

// ---------------- fp32 -> bf16 convert (vectorized) ----------------
__global__ void k_cvt(const float* __restrict__ in, short* __restrict__ out, int n4){
  int i = blockIdx.x * blockDim.x + threadIdx.x;
  if (i >= n4) return;
  float4 v = ((const float4*)in)[i];
  s16x4 o = { f2bf(v.x), f2bf(v.y), f2bf(v.z), f2bf(v.w) };
  *(s16x4*)(out + (size_t)i*4) = o;
}

// ---------------- fp32 [R][C] -> bf16 [C][R] transpose ----------------
__global__ void k_tcvt(const float* __restrict__ in, short* __restrict__ out, int R, int C){
  __shared__ float t[32][33];
  int c0 = blockIdx.x*32, r0 = blockIdx.y*32;
  int tx = threadIdx.x, ty = threadIdx.y;
  #pragma unroll
  for (int i=0;i<4;++i){
    int r = r0 + ty + i*8;
    t[ty + i*8][tx] = in[(size_t)r*C + c0 + tx];
  }
  __syncthreads();
  #pragma unroll
  for (int i=0;i<4;++i){
    int cc = c0 + ty + i*8;
    out[(size_t)cc*R + r0 + tx] = f2bf(t[tx][ty + i*8]);
  }
}

// ---------------- bf16 GEMM: C[M][N] = A[M][K] * Bt[N][K]^T + bias ----------------
template<int OUTF32>
__global__ __launch_bounds__(256) void k_gemm(const short* __restrict__ A,
    const short* __restrict__ Bt, const float* __restrict__ bias,
    short* __restrict__ outB, float* __restrict__ outF, int M, int N, int K)
{
  __shared__ short lds[128*64*2];   // A tile [128][64] then B tile [128][64]
  const int tid = threadIdx.x;
  const int lane = tid & 63, w = tid >> 6;
  const int g = lane >> 4, c = lane & 15;
  const int wm = (w >> 1) * 64, wn = (w & 1) * 64;
  const int bm = blockIdx.x * 128, bn = blockIdx.y * 128;

  f32x4 acc[4][4];
  #pragma unroll
  for (int i=0;i<4;++i)
    #pragma unroll
    for (int j=0;j<4;++j) acc[i][j] = (f32x4){0.f,0.f,0.f,0.f};

  const int nkt = K >> 6;
  for (int kt = 0; kt < nkt; ++kt){
    __syncthreads();
    #pragma unroll
    for (int i = 0; i < 8; ++i){
      const int seg   = w*8 + i;          // 0..31 ; segs 0-15 = A, 16-31 = B
      const int chunk = seg*64 + lane;    // 16-byte units
      const int local = chunk & 1023;
      const int row = local >> 3, kc = local & 7;
      const short* base = (chunk < 1024)
        ? (A  + (size_t)(bm + row) * K + kt*64)
        : (Bt + (size_t)(bn + row) * K + kt*64);
      const char* gaddr = (const char*)base + ((kc*16) ^ ((row & 7) << 4));
      load_lds16(gaddr, (char*)lds + seg*1024);
    }
    asm volatile("s_waitcnt vmcnt(0)" ::: "memory");
    __syncthreads();
    #pragma unroll
    for (int kk = 0; kk < 2; ++kk){
      s16x8 af[4], bfr[4];
      #pragma unroll
      for (int mi = 0; mi < 4; ++mi){
        int m = wm + mi*16 + c;
        int kb = (kk*64 + g*16) ^ ((m & 7) << 4);
        af[mi] = *(const s16x8*)((const char*)lds + m*128 + kb);
      }
      #pragma unroll
      for (int ni = 0; ni < 4; ++ni){
        int n = wn + ni*16 + c;
        int kb = (kk*64 + g*16) ^ ((n & 7) << 4);
        bfr[ni] = *(const s16x8*)((const char*)lds + 16384 + n*128 + kb);
      }
      #pragma unroll
      for (int mi = 0; mi < 4; ++mi)
        #pragma unroll
        for (int ni = 0; ni < 4; ++ni)
          acc[mi][ni] = mfma16(af[mi], bfr[ni], acc[mi][ni]);
    }
  }
  #pragma unroll
  for (int mi = 0; mi < 4; ++mi){
    #pragma unroll
    for (int ni = 0; ni < 4; ++ni){
      int col = bn + wn + ni*16 + c;
      float bv = bias[col];
      #pragma unroll
      for (int j = 0; j < 4; ++j){
        int rrow = bm + wm + mi*16 + g*4 + j;   // C/D: col=lane&15, row=4*(lane>>4)+j
        float v = acc[mi][ni][j] + bv;
        if (OUTF32) outF[(size_t)rrow * N + col] = v;
        else        outB[(size_t)rrow * N + col] = f2bf(v);
      }
    }
  }
}

// ---------------- RoPE on q,k parts of QKV -> Qr/Kr [B][H][S][D] ----------------
// Q pre-scaled by softmax_scale * log2(e): attention runs in exp2 domain.
__global__ void k_rope(const short* __restrict__ qkv, short* __restrict__ Qr,
                       short* __restrict__ Kr){
  const float QSC = 0.125f * 1.44269504088896340736f;
  int idx = blockIdx.x * 256 + threadIdx.x;   // B*S*H*32 = 2,097,152
  int i = idx & 31;
  int h = (idx >> 5) & 15;
  int s = (idx >> 9) & 2047;
  int b = idx >> 20;
  float inv = __builtin_amdgcn_exp2f(-(float)i * (13.287712379549449f / 32.0f)); // 10000^(-i/32)
  float ang = (float)s * inv;
  float cs = cosf(ang), sn = sinf(ang);
  size_t base = (size_t)(b*NS + s) * N3 + h*ND + 2*i;
  float x0 = bf2f(qkv[base]),      x1 = bf2f(qkv[base+1]);
  float y0 = bf2f(qkv[base+1024]), y1 = bf2f(qkv[base+1025]);
  size_t ob = ((size_t)(b*NH + h)*NS + s) * ND + 2*i;
  Qr[ob]   = f2bf((x0*cs - x1*sn) * QSC);
  Qr[ob+1] = f2bf((x1*cs + x0*sn) * QSC);
  Kr[ob]   = f2bf(y0*cs - y1*sn);
  Kr[ob+1] = f2bf(y1*cs + y0*sn);
}

// ---------------- V part of QKV -> Vt [B][H][D][S] (transposed) ----------------
__global__ void k_vtrans(const short* __restrict__ qkv, short* __restrict__ Vt){
  __shared__ short t[64][72];
  const int bid = blockIdx.x;                 // B*H*(S/64) = 1024
  const int sb = bid & 31, h = (bid>>5) & 15, b = bid >> 9;
  const int s0 = sb * 64;
  const int tid = threadIdx.x;
  #pragma unroll
  for (int it=0; it<2; ++it){
    int u = it*256 + tid;
    int r = u >> 3, cc = (u & 7) * 8;
    s16x8 v = *(const s16x8*)(qkv + (size_t)(b*NS + s0 + r)*N3 + 2048 + h*ND + cc);
    *(s16x8*)&t[r][cc] = v;
  }
  __syncthreads();
  #pragma unroll
  for (int it=0; it<2; ++it){
    int u = it*256 + tid;
    int d = u >> 3, sc2 = (u & 7) * 8;
    s16x8 v;
    #pragma unroll
    for (int j=0;j<8;++j) v[j] = t[sc2 + j][d];
    *(s16x8*)(Vt + ((size_t)(b*NH + h)*ND + d)*NS + s0 + sc2) = v;
  }
}

// ---------------- causal flash attention ----------------
// 4 waves/block, two q-tiles (qb, 31-qb) per block -> uniform 33 K-tiles.
// XCD-local head grouping: all 16 blocks of one (b,h) land on one XCD (bid%8
// round-robin heuristic) -> K/V stays in that XCD's L2 (2 MB working set).
// Triple-buffered K/V LDS staging (global_load_lds, XOR-swizzled source),
// prefetch depth 2, counted vmcnt(4), SINGLE raw s_barrier per iter (stage of
// t+2 issued post-barrier can't collide: all waves are within body t).
// Swapped QK^T and PV keep q lane-local; softmax reductions via permlane swaps.
#define PST 72   // P LDS row stride in shorts
__global__ __launch_bounds__(256) void k_attn(const short* __restrict__ Qr,
    const short* __restrict__ Kr, const short* __restrict__ Vt,
    short* __restrict__ Obuf)
{
  __shared__ short Kb[3][64*64];              // 24 KB
  __shared__ short Vb[3][64*64];              // 24 KB
  __shared__ short plds[4][16*PST];           // 9 KB
  const int tid = threadIdx.x;
  const int lane = tid & 63, w = tid >> 6;
  const int g = lane >> 4, c = lane & 15;
  const int bid = blockIdx.x;                 // 512
  const int xcd = bid & 7;
  const int qq  = bid >> 3;                   // 0..63
  const int gid = xcd + 8*(qq >> 4);          // 0..31: (b,h) group, XCD-local
  const int pid = qq & 15;
  const int h = gid & 15;
  const int b = gid >> 4;
  const size_t bh = (size_t)(b*NH + h);
  const short* Qbh = Qr + bh * (NS*ND);
  const short* Kbh = Kr + bh * (NS*ND);
  const short* Vbh = Vt + bh * (ND*NS);
  short* pw = &plds[w][0];
  char* pwb = (char*)pw;

  // ---- hoisted per-lane constants ----
  // staging source pointers (pre-swizzled); tile t adds t*8192 (K) / t*128 (V)
  const char* pK0[2]; const char* pV0[2];
  #pragma unroll
  for (int i=0;i<2;++i){
    int u = w*128 + i*64 + lane;              // 16B-chunk id 0..511
    int r = u >> 3, kc = u & 7;
    int sw = (kc*16) ^ ((r & 7) << 4);
    pK0[i] = (const char*)Kbh + r*128 + sw;
    pV0[i] = (const char*)Vbh + r*4096 + sw;
  }
  // LDS fragment read offsets (K and V share the same formula)
  int roff[4][2];
  #pragma unroll
  for (int f=0; f<4; ++f)
    #pragma unroll
    for (int kk=0; kk<2; ++kk)
      roff[f][kk] = (f*16 + c)*128 + ((kk*64 + g*16) ^ ((c & 7) << 4));
  // P write/read byte offsets
  int pwW[4], pwR[2];
  #pragma unroll
  for (int f=0; f<4; ++f) pwW[f] = (c*PST + f*16 + 4*g)*2;
  #pragma unroll
  for (int kk=0; kk<2; ++kk) pwR[kk] = (c*PST + kk*32 + g*8)*2;

  auto STAGE = [&](int tt, int bsel){
    #pragma unroll
    for (int i=0;i<2;++i){
      load_lds16(pK0[i] + (size_t)tt*8192, (char*)&Kb[bsel][0] + w*2048 + i*1024);
      load_lds16(pV0[i] + (size_t)tt*128,  (char*)&Vb[bsel][0] + w*2048 + i*1024);
    }
  };

  for (int ph = 0; ph < 2; ++ph){
    const int qb = ph ? (31 - pid) : pid;     // pair sums to 33 tiles -> uniform cost
    const int q0 = qb*64 + w*16;
    const int qglob = q0 + c;
    const int nkt = qb + 1;                   // uniform across the block's waves

    s16x8 qf0, qf1;
    {
      const short* qp = Qbh + (size_t)(q0 + c) * ND + g*8;
      qf0 = *(const s16x8*)(qp);
      qf1 = *(const s16x8*)(qp + 32);
    }
    f32x4 acc[4];
    #pragma unroll
    for (int dt=0; dt<4; ++dt) acc[dt] = (f32x4){0.f,0.f,0.f,0.f};
    float mrow = -3.0e38f, lrow = 0.f;

    if (ph){                                  // buf-0/1 reuse hazard vs ph0 tail
      __builtin_amdgcn_s_barrier();
      __builtin_amdgcn_sched_barrier(0);
    }
    STAGE(0, 0);
    if (nkt > 1) STAGE(1, 1);
    for (int t = 0; t < nkt; ++t){
      const int cur = t % 3;
      if (t == nkt-1) asm volatile("s_waitcnt vmcnt(0)" ::: "memory");
      else            asm volatile("s_waitcnt vmcnt(4)" ::: "memory"); // stage(t) done, t+1 in flight
      __builtin_amdgcn_s_barrier();           // single barrier per iter
      __builtin_amdgcn_sched_barrier(0);
      if (t + 2 < nkt) STAGE(t + 2, (t + 2) % 3);   // post-barrier: skew-safe
      const char* Kc = (const char*)&Kb[cur][0];
      const char* Vc = (const char*)&Vb[cur][0];
      // ---- QK^T: S^T[k][q] ----
      f32x4 st[4];
      __builtin_amdgcn_s_setprio(1);
      #pragma unroll
      for (int f=0; f<4; ++f){
        s16x8 k0 = *(const s16x8*)(Kc + roff[f][0]);
        s16x8 k1 = *(const s16x8*)(Kc + roff[f][1]);
        st[f] = (f32x4){0.f,0.f,0.f,0.f};
        st[f] = mfma16(k0, qf0, st[f]);
        st[f] = mfma16(k1, qf1, st[f]);
      }
      __builtin_amdgcn_s_setprio(0);
      // ---- causal mask: only the diagonal tile ----
      if (t == nkt-1){
        #pragma unroll
        for (int f=0; f<4; ++f)
          #pragma unroll
          for (int j=0; j<4; ++j){
            int kg = t*64 + f*16 + g*4 + j;
            if (kg > qglob) st[f][j] = -3.0e38f;
          }
      }
      // ---- online softmax (exp2 domain; q = c lane-local) ----
      float mf[4];
      #pragma unroll
      for (int f=0; f<4; ++f)
        mf[f] = fmaxf(fmaxf(st[f][0], st[f][1]), fmaxf(st[f][2], st[f][3]));
      float tm = fmaxf(fmaxf(mf[0], mf[1]), fmaxf(mf[2], mf[3]));
      tm = redmax64(tm);
      float mn = fmaxf(mrow, tm);
      float p[4][4];
      #pragma unroll
      for (int f=0; f<4; ++f)
        #pragma unroll
        for (int j=0; j<4; ++j) p[f][j] = __builtin_amdgcn_exp2f(st[f][j] - mn);
      // P -> LDS early (writes drain under the sum/rescale VALU)
      #pragma unroll
      for (int f=0; f<4; ++f){
        s16x4 pk = { f2bf(p[f][0]), f2bf(p[f][1]), f2bf(p[f][2]), f2bf(p[f][3]) };
        *(s16x4*)(pwb + pwW[f]) = pk;         // P[q=c][k=f*16+4g+j]
      }
      float sf[4];
      #pragma unroll
      for (int f=0; f<4; ++f)
        sf[f] = (p[f][0] + p[f][1]) + (p[f][2] + p[f][3]);
      float tl = redsum64((sf[0] + sf[1]) + (sf[2] + sf[3]));
      float alpha = __builtin_amdgcn_exp2f(mrow - mn);
      lrow = lrow*alpha + tl;
      mrow = mn;
      #pragma unroll
      for (int dt=0; dt<4; ++dt)
        #pragma unroll
        for (int j=0; j<4; ++j) acc[dt][j] *= alpha;   // lane-local alpha
      asm volatile("s_waitcnt lgkmcnt(0)" ::: "memory");
      __builtin_amdgcn_sched_barrier(0);
      s16x8 pa[2];
      #pragma unroll
      for (int kk=0; kk<2; ++kk)
        pa[kk] = *(const s16x8*)(pwb + pwR[kk]);
      // ---- PV: O^T[d][q] += V^T[d][k] * P^T[k][q] ----
      __builtin_amdgcn_s_setprio(1);
      #pragma unroll
      for (int dt=0; dt<4; ++dt)
        #pragma unroll
        for (int kk=0; kk<2; ++kk){
          s16x8 vfr = *(const s16x8*)(Vc + roff[dt][kk]);
          acc[dt] = mfma16(vfr, pa[kk], acc[dt]);
        }
      __builtin_amdgcn_s_setprio(0);
    }
    const float invl = 1.f / lrow;            // lane-local (q = c)
    #pragma unroll
    for (int dt=0; dt<4; ++dt){
      s16x4 ov = { f2bf(acc[dt][0]*invl), f2bf(acc[dt][1]*invl),
                   f2bf(acc[dt][2]*invl), f2bf(acc[dt][3]*invl) };
      *(s16x4*)(Obuf + (size_t)(b*NS + q0 + c)*NE + h*ND + dt*16 + 4*g) = ov;
    }
  }
}

extern "C" void kernel_launch(void* const* d_in, const int* in_sizes, int n_in,
                              void* d_out, int out_size, void* d_ws, size_t ws_size,
                              hipStream_t stream)
{
  const float* x     = (const float*)d_in[0];
  const float* w_qkv = (const float*)d_in[1];
  const float* b_qkv = (const float*)d_in[2];
  const float* w_o   = (const float*)d_in[3];
  const float* b_o   = (const float*)d_in[4];
  char* ws = (char*)d_ws;
  const size_t MB = 1u << 20;
  short* Xb    = (short*)(ws);            // 8 MB (reused as Obuf after GEMM1)
  short* Wqkvt = (short*)(ws + 8*MB);     // 6 MB
  short* Wot   = (short*)(ws + 14*MB);    // 2 MB
  short* QKV   = (short*)(ws + 16*MB);    // 24 MB
  short* Qrp   = (short*)(ws + 40*MB);    // 8 MB
  short* Krp   = (short*)(ws + 48*MB);    // 8 MB
  short* Vtp   = (short*)(ws + 56*MB);    // 8 MB  (total 64 MB)

  k_cvt<<<4096, 256, 0, stream>>>(x, Xb, (NB*NS*NE)/4);
  k_tcvt<<<dim3(N3/32, NE/32), dim3(32,8), 0, stream>>>(w_qkv, Wqkvt, NE, N3);
  k_tcvt<<<dim3(NE/32, NE/32), dim3(32,8), 0, stream>>>(w_o, Wot, NE, NE);
  k_gemm<0><<<dim3((NB*NS)/128, N3/128), 256, 0, stream>>>(Xb, Wqkvt, b_qkv, QKV, nullptr,
                                                           NB*NS, N3, NE);
  k_rope<<<(NB*NS*NH*32)/256, 256, 0, stream>>>(QKV, Qrp, Krp);
  k_vtrans<<<NB*NH*(NS/64), 256, 0, stream>>>(QKV, Vtp);
  k_attn<<<NB*NH*16, 256, 0, stream>>>(Qrp, Krp, Vtp, Xb);
  k_gemm<1><<<dim3((NB*NS)/128, NE/128), 256, 0, stream>>>(Xb, Wot, b_o, nullptr,
                                                           (float*)d_out, NB*NS, NE, NE);
}